// Round 4
// baseline (361.754 us; speedup 1.0000x reference)
//
#include <hip/hip_runtime.h>
#include <stdint.h>

// VQ Quantizer on MI355X. T=32768 tokens, K=8192 codes, C=256, fp32 in/out.
// Round 4: screen restructured — wave = 64 tokens x 16 codes (A persistent in
// 128 VGPRs, disjoint B slice per wave -> minimal LDS traffic), fragment-
// linear global layouts for conflict-free staging/frag-reads, cvt writes
// out3, rescore reads out3.  Screen key u = 0.5*e2 + 256 - x.e (A negated).
//   u32 key = (f32bits(u) & ~63) | nt ; per-split top-2 ; exact fp32 rescore.

#define T_TOT 32768
#define K_TOT 8192
#define CD    256
#define SPLITS 4
#define NSPLIT 2048
#define MT    64
#define NTI   32             // 64-code tiles per split
#define TILEH 16384          // halfs per tile (64 rows x 256)

typedef _Float16 h8 __attribute__((ext_vector_type(8)));
typedef _Float16 h4 __attribute__((ext_vector_type(4)));
typedef float f4 __attribute__((ext_vector_type(4)));
typedef unsigned long long u64;
typedef unsigned int u32;

// ws layout:
#define WS_AFT   0u            // _Float16 Aft[512 tiles][32 s][64 t][8]  16 MB (negated)
#define WS_BFT   16777216u     // _Float16 Bft[128 tiles][32 s][64 c][8]   4 MB
#define WS_E2    20971520u     // float [8192]
#define WS_E2B   21004288u     // float [8192]  (0.5*e2 + 256)
#define WS_CAND  21037056u     // u64 [32768][4][2]   2 MB
#define WS_NEED  23265280u

__device__ __forceinline__ u64 shfl_xor_u64(u64 v, int off, int w) {
  unsigned lo = (unsigned)v, hi = (unsigned)(v >> 32);
  lo = __shfl_xor(lo, off, w);
  hi = __shfl_xor(hi, off, w);
  return ((u64)hi << 32) | lo;
}
__device__ __forceinline__ u64 umin64(u64 a, u64 b) { return a < b ? a : b; }
__device__ __forceinline__ u64 umax64(u64 a, u64 b) { return a < b ? b : a; }
__device__ __forceinline__ u32 umin32(u32 a, u32 b) { return a < b ? a : b; }
__device__ __forceinline__ u32 umax32(u32 a, u32 b) { return a < b ? b : a; }

__device__ __forceinline__ void gll16(const void* g, void* l) {
  __builtin_amdgcn_global_load_lds(
      (const __attribute__((address_space(1))) void*)g,
      (__attribute__((address_space(3))) void*)l, 16, 0, 0);
}

// data[t,c] = in[(t>>10)*262144 + c*1024 + (t&1023)]  (NCHW -> [T,C])

// ============ main path ============

// NCHW fp32 -> Aft (fragment-linear negated fp16) + out3 (transposed data)
__global__ __launch_bounds__(256) void cvt_data_kernel(
    const float* __restrict__ in, _Float16* __restrict__ Aft,
    float* __restrict__ out3) {
  __shared__ float Ds[32][257];           // [token][dim], pitch 257
  const int tid = threadIdx.x;
  const int t0 = blockIdx.x * 32;
  const int nbase = (t0 >> 10) << 18;
  const int tin = t0 & 1023;

  // load: float4 over tokens (items: cc 0..255, t4 0..7)
  #pragma unroll
  for (int p = 0; p < 8; ++p) {
    const int item = p * 256 + tid;
    const int cc = item >> 3, t4 = (item & 7) * 4;
    const float4 v = *(const float4*)(in + nbase + cc * 1024 + tin + t4);
    Ds[t4 + 0][cc] = v.x; Ds[t4 + 1][cc] = v.y;
    Ds[t4 + 2][cc] = v.z; Ds[t4 + 3][cc] = v.w;
  }
  __syncthreads();

  // out3: coalesced rows
  #pragma unroll 8
  for (int tt = 0; tt < 32; ++tt)
    out3[(u64)(t0 + tt) * CD + tid] = Ds[tt][tid];

  // Aft: items (s 0..31, tt 0..31), negated fp16, h8 stores
  const u64 tbase = (u64)(t0 >> 6) * TILEH + (u64)(t0 & 63) * 8;
  #pragma unroll
  for (int p = 0; p < 4; ++p) {
    const int item = p * 256 + tid;
    const int s = item >> 5, tt = item & 31;
    h8 hv;
    #pragma unroll
    for (int j = 0; j < 8; ++j) hv[j] = (_Float16)(-Ds[tt][s * 8 + j]);
    *(h8*)(Aft + tbase + s * 512 + tt * 8) = hv;
  }
}

// codebook fp32 -> Bft (fragment-linear fp16), e2 exact, e2b = 0.5*e2 + 256
__global__ __launch_bounds__(256) void cvt_cb_kernel(
    const float* __restrict__ cb, _Float16* __restrict__ Bft,
    float* __restrict__ e2, float* __restrict__ e2b) {
  const int tid = threadIdx.x;
  const int w = tid >> 6, lane = tid & 63;
  const int tile = blockIdx.x;
  const int c0 = tile * 64;
  const int s = lane >> 1, off4 = (lane & 1) * 4;
  #pragma unroll 4
  for (int i = 0; i < 16; ++i) {
    const int r = i * 4 + w;                     // local code 0..63
    const float4 v = *(const float4*)(cb + (u64)(c0 + r) * CD + lane * 4);
    h4 hv; hv[0] = (_Float16)v.x; hv[1] = (_Float16)v.y;
    hv[2] = (_Float16)v.z; hv[3] = (_Float16)v.w;
    *(h4*)(Bft + (u64)tile * TILEH + s * 512 + r * 8 + off4) = hv;
    float sum = v.x * v.x + v.y * v.y + v.z * v.z + v.w * v.w;
    #pragma unroll
    for (int o = 32; o >= 1; o >>= 1) sum += __shfl_xor(sum, o, 64);
    if (lane == 0) { e2[c0 + r] = sum; e2b[c0 + r] = 0.5f * sum + 256.0f; }
  }
}

// screen: block = 64 tokens x one split; wave = 64 tokens x 16 codes
__global__ __launch_bounds__(256, 2) void screen_kernel(
    const _Float16* __restrict__ Aft, const _Float16* __restrict__ Bft,
    const float* __restrict__ e2b, u64* __restrict__ cand) {
  __shared__ __align__(16) _Float16 smem[2 * TILEH];   // 64 KB

  const int tid = threadIdx.x;
  const int lane = tid & 63;
  const int w = tid >> 6;          // wave id: codes [w*16, +16) of each tile
  const int q = lane >> 4;
  const int c15 = lane & 15;

  const int bm = blockIdx.x & 511;
  const int split = blockIdx.x >> 9;
  const int t0 = bm * MT;
  const int n0s = split * NSPLIT;
  const int btile0 = split * NTI;

  _Float16* buf0 = smem;
  _Float16* buf1 = smem + TILEH;

  // ---- prologue: A tile -> buf0 -> af regs; B tile 0 -> buf1 ----
  {
    const _Float16* Atile = Aft + (u64)bm * TILEH;
    #pragma unroll
    for (int ii = 0; ii < 8; ++ii) {
      const int i = w * 8 + ii;
      gll16(Atile + i * 512 + lane * 8, buf0 + i * 512);
    }
  }
  __syncthreads();

  h8 af[4][8];
  #pragma unroll
  for (int mi = 0; mi < 4; ++mi) {
    const int m = mi * 16 + c15;
    #pragma unroll
    for (int kk = 0; kk < 8; ++kk)
      af[mi][kk] = *(const h8*)(buf0 + (kk * 4 + q) * 512 + m * 8);
  }

  {
    const _Float16* Btile = Bft + (u64)btile0 * TILEH;
    #pragma unroll
    for (int ii = 0; ii < 8; ++ii) {
      const int i = w * 8 + ii;
      gll16(Btile + i * 512 + lane * 8, buf1 + i * 512);
    }
  }

  const float* e2bs = e2b + n0s + w * 16 + c15;
  float ev = e2bs[0];

  u32 m1[16], m2[16];
  #pragma unroll
  for (int r = 0; r < 16; ++r) { m1[r] = 0xffffffffu; m2[r] = 0xffffffffu; }

  __syncthreads();

  const int nb8 = (w * 16 + c15) * 8;
  for (int nt = 0; nt < NTI; ++nt) {
    _Float16* cur = (nt & 1) ? buf0 : buf1;
    _Float16* nxt = (nt & 1) ? buf1 : buf0;

    if (nt < NTI - 1) {
      const _Float16* Btile = Bft + (u64)(btile0 + nt + 1) * TILEH;
      #pragma unroll
      for (int ii = 0; ii < 8; ++ii) {
        const int i = w * 8 + ii;
        gll16(Btile + i * 512 + lane * 8, nxt + i * 512);
      }
    }
    const float evn = e2bs[(nt < NTI - 1 ? nt + 1 : nt) * 64];

    f4 acc[4];
    #pragma unroll
    for (int mi = 0; mi < 4; ++mi) acc[mi] = (f4){ev, ev, ev, ev};

    #pragma unroll
    for (int kk = 0; kk < 8; ++kk) {
      const h8 bf = *(const h8*)(cur + (kk * 4 + q) * 512 + nb8);
      acc[0] = __builtin_amdgcn_mfma_f32_16x16x32_f16(af[0][kk], bf, acc[0], 0, 0, 0);
      acc[1] = __builtin_amdgcn_mfma_f32_16x16x32_f16(af[1][kk], bf, acc[1], 0, 0, 0);
      acc[2] = __builtin_amdgcn_mfma_f32_16x16x32_f16(af[2][kk], bf, acc[2], 0, 0, 0);
      acc[3] = __builtin_amdgcn_mfma_f32_16x16x32_f16(af[3][kk], bf, acc[3], 0, 0, 0);
    }

    // top-2 insert: 16 token-slots, all same code (lane-fixed), idx = nt
    #pragma unroll
    for (int mi = 0; mi < 4; ++mi)
      #pragma unroll
      for (int reg = 0; reg < 4; ++reg) {
        const int r = mi * 4 + reg;
        const u32 key = (__float_as_uint(acc[mi][reg]) & ~63u) | (u32)nt;
        const u32 t = umax32(m1[r], key);
        m1[r] = umin32(m1[r], key);
        m2[r] = umin32(m2[r], t);
      }
    ev = evn;
    __syncthreads();
  }

  // ---- merge across the 16 c15 lanes of each quad ----
  const u32 cbase = (u32)(n0s + w * 16 + c15);
  u64 P1[16], P2[16];
  #pragma unroll
  for (int r = 0; r < 16; ++r) {
    P1[r] = ((u64)m1[r] << 32) | (cbase + ((m1[r] & 63u) << 6));
    P2[r] = ((u64)m2[r] << 32) | (cbase + ((m2[r] & 63u) << 6));
  }
  #pragma unroll
  for (int st = 1; st < 16; st <<= 1) {
    #pragma unroll
    for (int r = 0; r < 16; ++r) {
      const u64 o1 = shfl_xor_u64(P1[r], st, 16);
      const u64 o2 = shfl_xor_u64(P2[r], st, 16);
      const u64 n1 = umin64(P1[r], o1);
      const u64 hi = umax64(P1[r], o1);
      P2[r] = umin64(hi, umin64(P2[r], o2));
      P1[r] = n1;
    }
  }

  u64* mbuf = (u64*)smem;            // [4 waves][64 tokens][2]
  if (c15 == 0) {
    #pragma unroll
    for (int r = 0; r < 16; ++r) {
      const int token = (r >> 2) * 16 + q * 4 + (r & 3);
      mbuf[(w * 64 + token) * 2 + 0] = P1[r];
      mbuf[(w * 64 + token) * 2 + 1] = P2[r];
    }
  }
  __syncthreads();
  if (tid < 64) {
    u64 a1 = mbuf[tid * 2], a2 = mbuf[tid * 2 + 1];
    #pragma unroll
    for (int ww = 1; ww < 4; ++ww) {
      const u64 b1 = mbuf[(ww * 64 + tid) * 2];
      const u64 b2 = mbuf[(ww * 64 + tid) * 2 + 1];
      const u64 n1 = umin64(a1, b1);
      a2 = umin64(umax64(a1, b1), umin64(a2, b2));
      a1 = n1;
    }
    cand[(u64)(t0 + tid) * 8 + split * 2 + 0] = a1;
    cand[(u64)(t0 + tid) * 8 + split * 2 + 1] = a2;
  }
}

// fused: exact fp32 rescore of 8 candidates (reads out3) + write out1/out2
__global__ __launch_bounds__(256) void rescore_output_kernel(
    const float* __restrict__ out3, const float* __restrict__ cb,
    const float* __restrict__ e2, const u64* __restrict__ cand,
    float* __restrict__ out) {
  __shared__ __align__(16) float Ds[32][260];
  __shared__ int idxs[32];
  const int tid = threadIdx.x;
  const int t0 = blockIdx.x * 32;
  #pragma unroll
  for (int p = 0; p < 8; ++p) {
    const int item = p * 256 + tid;
    const int tt = item >> 6, c4 = (item & 63) * 4;
    const float4 v = *(const float4*)(out3 + (u64)(t0 + tt) * CD + c4);
    *(float4*)&Ds[tt][c4] = v;
  }
  __syncthreads();
  const int w = tid >> 6, lane = tid & 63;
  for (int s = 0; s < 8; ++s) {
    const int tt = w * 8 + s;
    const int t = t0 + tt;
    int colv = 0;
    if (lane < 8) colv = (int)(u32)cand[(u64)t * 8 + lane];
    const float4 x = *(const float4*)&Ds[tt][lane * 4];
    float bestd = 1e30f; int bestc = 0x7fffffff;
    #pragma unroll
    for (int j = 0; j < 8; ++j) {
      const int col = __shfl(colv, j, 64);
      const float4 e = *(const float4*)(cb + (u64)col * CD + lane * 4);
      float p4 = x.x * e.x + x.y * e.y + x.z * e.z + x.w * e.w;
      #pragma unroll
      for (int off = 32; off >= 1; off >>= 1) p4 += __shfl_xor(p4, off, 64);
      const float d = e2[col] - 2.0f * p4;
      if (d < bestd || (d == bestd && col < bestc)) { bestd = d; bestc = col; }
    }
    if (lane == 0) idxs[tt] = bestc;
  }
  __syncthreads();
  float* out1 = out;
  float* out2 = out + 8388608;
  for (int tt = 0; tt < 32; ++tt) {
    const float d = Ds[tt][tid];
    const int k = idxs[tt];
    const float qv = cb[(u64)k * CD + tid];
    const float qd = d + (qv - d);
    const int o = (t0 + tt) * CD + tid;
    out1[o] = qv;
    out2[o] = qd;
  }
}

// ============ fallback path (exact fp32), used if ws too small ============

__global__ __launch_bounds__(256) void norms_kernel(const float* __restrict__ in,
                                                    const float* __restrict__ cb,
                                                    float* __restrict__ e2,
                                                    float* __restrict__ x2) {
  const int b = blockIdx.x;
  const int tid = threadIdx.x;
  if (b < 2048) {
    const int wave = tid >> 6, lane = tid & 63;
    const int row = b * 4 + wave;
    const float4 v = *(const float4*)(cb + row * CD + lane * 4);
    float s = v.x * v.x + v.y * v.y + v.z * v.z + v.w * v.w;
    #pragma unroll
    for (int off = 32; off >= 1; off >>= 1) s += __shfl_down(s, off, 64);
    if (lane == 0) e2[row] = s;
  } else {
    const int t = (b - 2048) * 256 + tid;
    const float* p = in + ((t >> 10) << 18) + (t & 1023);
    float s = 0.f;
    #pragma unroll 8
    for (int c = 0; c < CD; ++c) { const float v = p[c << 10]; s += v * v; }
    x2[t] = s;
  }
}

__global__ __launch_bounds__(256) void dist_argmin_kernel(
    const float* __restrict__ in, const float* __restrict__ cb,
    const float* __restrict__ e2, const float* __restrict__ x2,
    u64* __restrict__ packed) {
  __shared__ __align__(16) float As_[32][128];
  __shared__ __align__(16) float Bs_[32][128];
  const int tid = threadIdx.x;
  const int tx = tid & 15, ty = tid >> 4;
  const int tb = blockIdx.x & 255;
  const int ks = blockIdx.x >> 8;
  const int t0 = tb * 128;
  const int nbase = (t0 >> 10) << 18;
  const int tin = t0 & 1023;
  float xi[8];
  #pragma unroll
  for (int i = 0; i < 8; ++i)
    xi[i] = x2[t0 + ty * 4 + (i & 3) + ((i >> 2) << 6)];
  u64 best[8];
  #pragma unroll
  for (int i = 0; i < 8; ++i) best[i] = ~0ull;
  for (int kt = 0; kt < 32; ++kt) {
    const int k0 = ks * 4096 + kt * 128;
    float acc[8][8];
    #pragma unroll
    for (int i = 0; i < 8; ++i)
      #pragma unroll
      for (int j = 0; j < 8; ++j) acc[i][j] = 0.f;
    float ej[8];
    #pragma unroll
    for (int j = 0; j < 8; ++j)
      ej[j] = e2[k0 + tx * 4 + (j & 3) + ((j >> 2) << 6)];
    for (int ch = 0; ch < 8; ++ch) {
      const int c0 = ch * 32;
      #pragma unroll
      for (int p = 0; p < 4; ++p) {
        const int l = p * 1024 + tid * 4;
        const int cc = l >> 7, tt = l & 127;
        *(float4*)&As_[cc][tt] =
            *(const float4*)(in + nbase + (c0 + cc) * 1024 + tin + tt);
      }
      #pragma unroll
      for (int p = 0; p < 4; ++p) {
        const int ix = p * 256 + tid;
        const int kk = ix >> 3, cs = (ix & 7) * 4;
        const float4 v = *(const float4*)(cb + (k0 + kk) * CD + c0 + cs);
        Bs_[cs + 0][kk] = v.x; Bs_[cs + 1][kk] = v.y;
        Bs_[cs + 2][kk] = v.z; Bs_[cs + 3][kk] = v.w;
      }
      __syncthreads();
      #pragma unroll
      for (int cc = 0; cc < 32; ++cc) {
        const float4 a0 = *(const float4*)&As_[cc][ty * 4];
        const float4 a1 = *(const float4*)&As_[cc][64 + ty * 4];
        const float4 b0 = *(const float4*)&Bs_[cc][tx * 4];
        const float4 b1 = *(const float4*)&Bs_[cc][64 + tx * 4];
        const float a[8]  = {a0.x, a0.y, a0.z, a0.w, a1.x, a1.y, a1.z, a1.w};
        const float bb[8] = {b0.x, b0.y, b0.z, b0.w, b1.x, b1.y, b1.z, b1.w};
        #pragma unroll
        for (int i = 0; i < 8; ++i)
          #pragma unroll
          for (int j = 0; j < 8; ++j)
            acc[i][j] += a[i] * bb[j];
      }
      __syncthreads();
    }
    #pragma unroll
    for (int i = 0; i < 8; ++i) {
      u64 m = best[i];
      #pragma unroll
      for (int j = 0; j < 8; ++j) {
        const float dist = (xi[i] - 2.0f * acc[i][j]) + ej[j];
        const int kidx = k0 + tx * 4 + (j & 3) + ((j >> 2) << 6);
        const u64 pk = ((u64)__float_as_uint(dist) << 32) | (unsigned)kidx;
        m = pk < m ? pk : m;
      }
      best[i] = m;
    }
  }
  #pragma unroll
  for (int i = 0; i < 8; ++i) {
    u64 m = best[i];
    #pragma unroll
    for (int off = 8; off >= 1; off >>= 1) {
      const u64 o = shfl_xor_u64(m, off, 16);
      m = o < m ? o : m;
    }
    if (tx == 0)
      atomicMin(&packed[t0 + ty * 4 + (i & 3) + ((i >> 2) << 6)], m);
  }
}

__global__ __launch_bounds__(256) void output_kernel(
    const float* __restrict__ in, const float* __restrict__ cb,
    const u64* __restrict__ packed, float* __restrict__ out) {
  __shared__ float Ds[32][257];
  __shared__ int idxs[32];
  const int tid = threadIdx.x;
  const int t0 = blockIdx.x * 32;
  const int nbase = (t0 >> 10) << 18;
  const int tin = t0 & 1023;
  if (tid < 32) idxs[tid] = (int)(packed[t0 + tid] & 0xffffffffull);
  #pragma unroll 8
  for (int p = 0; p < 32; ++p) {
    const int lin = p * 256 + tid;
    const int cc = lin >> 5, tt = lin & 31;
    Ds[tt][cc] = in[nbase + cc * 1024 + tin + tt];
  }
  __syncthreads();
  float* out1 = out;
  float* out2 = out + 8388608;
  float* out3 = out + 16777216;
  for (int tt = 0; tt < 32; ++tt) {
    const float d = Ds[tt][tid];
    const int k = idxs[tt];
    const float q = cb[k * CD + tid];
    const float qd = d + (q - d);
    const int o = (t0 + tt) * CD + tid;
    out1[o] = q;
    out2[o] = qd;
    out3[o] = d;
  }
}

extern "C" void kernel_launch(void* const* d_in, const int* in_sizes, int n_in,
                              void* d_out, int out_size, void* d_ws, size_t ws_size,
                              hipStream_t stream) {
  const float* in = (const float*)d_in[0];
  const float* cb = (const float*)d_in[1];
  float* out = (float*)d_out;

  if (ws_size >= WS_NEED) {
    _Float16* Aft = (_Float16*)((char*)d_ws + WS_AFT);
    _Float16* Bft = (_Float16*)((char*)d_ws + WS_BFT);
    float* e2  = (float*)((char*)d_ws + WS_E2);
    float* e2b = (float*)((char*)d_ws + WS_E2B);
    u64* cand  = (u64*)((char*)d_ws + WS_CAND);
    float* out3 = out + 16777216;

    cvt_data_kernel<<<T_TOT / 32, 256, 0, stream>>>(in, Aft, out3);
    cvt_cb_kernel<<<K_TOT / 64, 256, 0, stream>>>(cb, Bft, e2, e2b);
    screen_kernel<<<(T_TOT / MT) * SPLITS, 256, 0, stream>>>(Aft, Bft, e2b, cand);
    rescore_output_kernel<<<T_TOT / 32, 256, 0, stream>>>(out3, cb, e2, cand, out);
  } else {
    u64* packed = (u64*)d_ws;
    float* e2 = (float*)((char*)d_ws + 262144);
    float* x2 = (float*)((char*)d_ws + 294912);
    hipMemsetAsync(packed, 0xFF, T_TOT * sizeof(u64), stream);
    norms_kernel<<<2176, 256, 0, stream>>>(in, cb, e2, x2);
    dist_argmin_kernel<<<512, 256, 0, stream>>>(in, cb, e2, x2, packed);
    output_kernel<<<T_TOT / 32, 256, 0, stream>>>(in, cb, packed, out);
  }
}